// Round 1
// baseline (534.684 us; speedup 1.0000x reference)
//
#include <hip/hip_runtime.h>

// Problem constants (BuNN layer)
#define CC   512      // channels
#define BB_  128      // bundles (4 channels each: [i=2][t=2])
#define GEMM_MT 64
#define GEMM_NT 64
#define GEMM_KT 32

typedef __attribute__((ext_vector_type(8))) short short8;
typedef __attribute__((ext_vector_type(4))) float f32x4;
typedef __attribute__((ext_vector_type(2))) float f32x2;
typedef __attribute__((ext_vector_type(4))) unsigned short u16x4;

__device__ __forceinline__ unsigned short f2bf(float f) {
  union { float f; unsigned u; } v; v.f = f;
  return (unsigned short)((v.u + 0x7FFFu + ((v.u >> 16) & 1u)) >> 16);
}

// ---------------- graph prep ----------------
__global__ void k_count(const int* __restrict__ src, const int* __restrict__ dst,
                        int* __restrict__ cnt_src, int* __restrict__ cnt_dst, int E) {
  int e = blockIdx.x * blockDim.x + threadIdx.x;
  if (e < E) {
    atomicAdd(&cnt_src[src[e]], 1);
    atomicAdd(&cnt_dst[dst[e]], 1);
  }
}

__global__ void k_deginv(const int* __restrict__ cnt, float* __restrict__ dinv, int n) {
  int i = blockIdx.x * blockDim.x + threadIdx.x;
  if (i < n) dinv[i] = 1.0f / (float)cnt[i];
}

__global__ __launch_bounds__(1024) void k_scan(const int* __restrict__ cnt,
                                               int* __restrict__ rp, int n) {
  __shared__ int sm[1024];
  int tid = threadIdx.x;
  int chunk = (n + 1023) >> 10;
  int beg = tid * chunk;
  int end = beg + chunk; if (end > n) end = n;
  int s = 0;
  for (int i = beg; i < end && i < n; ++i) s += cnt[i];
  sm[tid] = s;
  __syncthreads();
  for (int off = 1; off < 1024; off <<= 1) {
    int v = (tid >= off) ? sm[tid - off] : 0;
    __syncthreads();
    sm[tid] += v;
    __syncthreads();
  }
  int run = (tid == 0) ? 0 : sm[tid - 1];
  for (int i = beg; i < end && i < n; ++i) { rp[i] = run; run += cnt[i]; }
  if (tid == 0) rp[n] = sm[1023];
}

__global__ void k_fill(const int* __restrict__ src, const int* __restrict__ dst,
                       const int* __restrict__ rp, int* __restrict__ fil,
                       int* __restrict__ col, int E) {
  int e = blockIdx.x * blockDim.x + threadIdx.x;
  if (e < E) {
    int d = dst[e];
    int p = atomicAdd(&fil[d], 1);
    col[rp[d] + p] = src[e];
  }
}

// ---------------- converts ----------------
// f32 [validRows][CC] -> bf16 [mpad][CC], zero padding rows (never reads past validRows)
__global__ void k_conv_bf16(const float* __restrict__ in, unsigned short* __restrict__ out,
                            int validRows, int total4) {
  int i4 = blockIdx.x * blockDim.x + threadIdx.x;
  if (i4 >= total4) return;
  int row = i4 / (CC / 4);
  u16x4 o;
  if (row < validRows) {
    f32x4 v = ((const f32x4*)in)[i4];
    o[0] = f2bf(v[0]); o[1] = f2bf(v[1]); o[2] = f2bf(v[2]); o[3] = f2bf(v[3]);
  } else {
    o[0] = 0; o[1] = 0; o[2] = 0; o[3] = 0;
  }
  ((u16x4*)out)[i4] = o;
}

// W [K][Nw] f32  ->  Wt [Nw][K] bf16   (tiled transpose)
__global__ void k_transconv(const float* __restrict__ W, unsigned short* __restrict__ Wt,
                            int K, int Nw) {
  __shared__ float tile[32][33];
  int n0 = blockIdx.x * 32, k0 = blockIdx.y * 32;
  int tx = threadIdx.x, ty = threadIdx.y;          // 32 x 8
  for (int j = 0; j < 4; ++j)
    tile[ty + j * 8][tx] = W[(k0 + ty + j * 8) * Nw + n0 + tx];
  __syncthreads();
  for (int j = 0; j < 4; ++j)
    Wt[(n0 + ty + j * 8) * K + k0 + tx] = f2bf(tile[tx][ty + j * 8]);
}

// ---------------- GEMM: out = A[M][K](bf16) x Bt[Nw][K]^T(bf16) + bias ----------------
// EPI 0: f32 store; EPI 1: GELU(exact)->bf16 store; EPI 2: theta -> (cos,sin) float2 store
template <int EPI>
__global__ __launch_bounds__(256) void k_gemm(const unsigned short* __restrict__ A,
                                              const unsigned short* __restrict__ Bt,
                                              const float* __restrict__ bias,
                                              void* __restrict__ outp,
                                              int K, int Nw) {
  __shared__ unsigned short As[GEMM_MT][GEMM_KT + 8];  // +8 pad -> 80B rows, conflict-light
  __shared__ unsigned short Bs[GEMM_NT][GEMM_KT + 8];
  int m0 = blockIdx.x * GEMM_MT;
  int n0 = blockIdx.y * GEMM_NT;
  int tid = threadIdx.x;
  int wid = tid >> 6, lane = tid & 63;
  int wr = wid >> 1, wc = wid & 1;
  int l15 = lane & 15, kg = lane >> 4;
  int srow = tid >> 2, sseg = tid & 3;
  f32x4 acc[2][2] = {};

  for (int kt = 0; kt < K; kt += GEMM_KT) {
    *(short8*)&As[srow][sseg * 8] = *(const short8*)&A[(size_t)(m0 + srow) * K + kt + sseg * 8];
    *(short8*)&Bs[srow][sseg * 8] = *(const short8*)&Bt[(size_t)(n0 + srow) * K + kt + sseg * 8];
    __syncthreads();
    short8 af0 = *(const short8*)&As[wr * 32 + l15][kg * 8];
    short8 af1 = *(const short8*)&As[wr * 32 + 16 + l15][kg * 8];
    short8 bf0 = *(const short8*)&Bs[wc * 32 + l15][kg * 8];
    short8 bf1 = *(const short8*)&Bs[wc * 32 + 16 + l15][kg * 8];
    acc[0][0] = __builtin_amdgcn_mfma_f32_16x16x32_bf16(af0, bf0, acc[0][0], 0, 0, 0);
    acc[0][1] = __builtin_amdgcn_mfma_f32_16x16x32_bf16(af0, bf1, acc[0][1], 0, 0, 0);
    acc[1][0] = __builtin_amdgcn_mfma_f32_16x16x32_bf16(af1, bf0, acc[1][0], 0, 0, 0);
    acc[1][1] = __builtin_amdgcn_mfma_f32_16x16x32_bf16(af1, bf1, acc[1][1], 0, 0, 0);
    __syncthreads();
  }

  for (int mi = 0; mi < 2; ++mi)
    for (int ni = 0; ni < 2; ++ni)
      for (int r = 0; r < 4; ++r) {
        int row = m0 + wr * 32 + mi * 16 + kg * 4 + r;   // C/D: row=(lane>>4)*4+reg
        int colL = n0 + wc * 32 + ni * 16 + l15;         // C/D: col=lane&15
        float v = acc[mi][ni][r] + bias[colL];
        if (EPI == 0) {
          ((float*)outp)[(size_t)row * Nw + colL] = v;
        } else if (EPI == 1) {
          float g = 0.5f * v * (1.0f + erff(v * 0.70710678118654752f));
          ((unsigned short*)outp)[(size_t)row * Nw + colL] = f2bf(g);
        } else {
          float sv, cv;
          sincosf(v, &sv, &cv);
          f32x2 o; o[0] = cv; o[1] = sv;
          ((f32x2*)outp)[(size_t)row * Nw + colL] = o;
        }
      }
}

// ---------------- bundle rotation ----------------
// h = R x  (per bundle b: v=[v00,v01,v10,v11]; R=[[c,-s],[s,c]] acting on i index)
__global__ void k_rotate(const float* __restrict__ x, const f32x2* __restrict__ cs,
                         float* __restrict__ h, float* __restrict__ cur, int nb) {
  int idx = blockIdx.x * blockDim.x + threadIdx.x;
  if (idx >= nb) return;
  f32x2 a = cs[idx];
  float c = a[0], s = a[1];
  f32x4 v = ((const f32x4*)x)[idx];
  f32x4 o;
  o[0] = c * v[0] - s * v[2];
  o[1] = c * v[1] - s * v[3];
  o[2] = s * v[0] + c * v[2];
  o[3] = s * v[1] + c * v[3];
  ((f32x4*)h)[idx] = o;
  ((f32x4*)cur)[idx] = o;
}

// out = x + R^T h2
__global__ void k_rotback(const float* __restrict__ x, const f32x2* __restrict__ cs,
                          const float* __restrict__ h2, float* __restrict__ out, int nb) {
  int idx = blockIdx.x * blockDim.x + threadIdx.x;
  if (idx >= nb) return;
  f32x2 a = cs[idx];
  float c = a[0], s = a[1];
  f32x4 v = ((const f32x4*)h2)[idx];
  f32x4 xx = ((const f32x4*)x)[idx];
  f32x4 o;
  o[0] = xx[0] + c * v[0] + s * v[2];
  o[1] = xx[1] + c * v[1] + s * v[3];
  o[2] = xx[2] - s * v[0] + c * v[2];
  o[3] = xx[3] - s * v[1] + c * v[3];
  ((f32x4*)out)[idx] = o;
}

// ---------------- diffusion: nxt = coef*(cur - dinv[v]*sum_in(cur)); h += nxt ----------------
__global__ __launch_bounds__(128) void k_diffuse(const float* __restrict__ cur,
                                                 float* __restrict__ nxt,
                                                 float* __restrict__ h,
                                                 const float* __restrict__ dinv,
                                                 const int* __restrict__ rp,
                                                 const int* __restrict__ col,
                                                 float coef, int n) {
  int v = blockIdx.x;
  if (v >= n) return;
  int t = threadIdx.x;
  int beg = rp[v], end = rp[v + 1];
  f32x4 s = {0.f, 0.f, 0.f, 0.f};
  for (int e = beg; e < end; ++e) {
    int u = col[e];
    s += ((const f32x4*)cur)[(size_t)u * (CC / 4) + t];
  }
  size_t o = (size_t)v * (CC / 4) + t;
  f32x4 c = ((const f32x4*)cur)[o];
  float di = dinv[v];
  f32x4 nv = (c - s * di) * coef;
  ((f32x4*)nxt)[o] = nv;
  ((f32x4*)h)[o] = ((const f32x4*)h)[o] + nv;
}

// ---------------- batch norm ----------------
__global__ __launch_bounds__(512) void k_stats(const float* __restrict__ out,
                                               float* __restrict__ sum, float* __restrict__ sumsq,
                                               int n) {
  int c = threadIdx.x;
  float s = 0.f, s2 = 0.f;
  for (int r = blockIdx.x; r < n; r += gridDim.x) {
    float v = out[(size_t)r * CC + c];
    s += v; s2 += v * v;
  }
  atomicAdd(&sum[c], s);
  atomicAdd(&sumsq[c], s2);
}

__global__ void k_bnfinal(const float* __restrict__ sum, const float* __restrict__ sumsq,
                          const float* __restrict__ gamma, const float* __restrict__ beta,
                          float* __restrict__ scale, float* __restrict__ shift, int n) {
  int c = threadIdx.x;
  float inv = 1.0f / (float)n;
  float mean = sum[c] * inv;
  float var = sumsq[c] * inv - mean * mean;
  float sc = gamma[c] * rsqrtf(var + 1e-5f);
  scale[c] = sc;
  shift[c] = beta[c] - mean * sc;
}

__global__ void k_norm(float* __restrict__ out, const float* __restrict__ scale,
                       const float* __restrict__ shift, int n4) {
  int i = blockIdx.x * blockDim.x + threadIdx.x;
  if (i >= n4) return;
  int c4 = i & (CC / 4 - 1);
  f32x4 v = ((f32x4*)out)[i];
  f32x4 sc = ((const f32x4*)scale)[c4];
  f32x4 sh = ((const f32x4*)shift)[c4];
  ((f32x4*)out)[i] = v * sc + sh;
}

// ---------------- orchestration ----------------
extern "C" void kernel_launch(void* const* d_in, const int* in_sizes, int n_in,
                              void* d_out, int out_size, void* d_ws, size_t ws_size,
                              hipStream_t stream) {
  (void)n_in; (void)out_size; (void)ws_size;
  const float* x    = (const float*)d_in[0];
  const float* W1   = (const float*)d_in[1];
  const float* b1   = (const float*)d_in[2];
  const float* W2   = (const float*)d_in[3];
  const float* b2   = (const float*)d_in[4];
  const float* Wlin = (const float*)d_in[5];
  const float* blin = (const float*)d_in[6];
  const float* gamma = (const float*)d_in[7];
  const float* beta  = (const float*)d_in[8];
  const int*   ei    = (const int*)d_in[9];

  const int n   = in_sizes[0] / CC;          // 20000
  const int E   = in_sizes[9] / 2;           // 160000
  const int GNN = in_sizes[2];               // 512  (b1 size)
  const int NBP = in_sizes[4];               // 128  (b2 size)
  const int* src = ei;
  const int* dst = ei + E;
  const int mtiles = (n + GEMM_MT - 1) / GEMM_MT;
  const int mpad = mtiles * GEMM_MT;         // 20032

  char* ws = (char*)d_ws;
  size_t off = 0;
  auto alloc = [&](size_t bytes) -> void* {
    void* p = ws + off;
    off = (off + bytes + 255) & ~(size_t)255;
    return p;
  };
  int*   cnt_src = (int*)alloc((size_t)n * 4);
  int*   cnt_dst = (int*)alloc((size_t)n * 4);
  int*   fil     = (int*)alloc((size_t)n * 4);
  int*   rp      = (int*)alloc((size_t)(n + 1) * 4);
  int*   colx    = (int*)alloc((size_t)E * 4);
  float* dinv    = (float*)alloc((size_t)n * 4);
  float* colsum  = (float*)alloc(CC * 4);
  float* colsq   = (float*)alloc(CC * 4);
  float* scale   = (float*)alloc(CC * 4);
  float* shift   = (float*)alloc(CC * 4);
  unsigned short* W1t = (unsigned short*)alloc((size_t)GNN * CC * 2);   // [GNN][C]
  unsigned short* W2t = (unsigned short*)alloc((size_t)NBP * GNN * 2);  // [NBP][GNN]
  unsigned short* Wlt = (unsigned short*)alloc((size_t)CC * CC * 2);    // [C][C]
  f32x2* cs   = (f32x2*)alloc((size_t)mpad * BB_ * 8);
  float* BUF0 = (float*)alloc((size_t)mpad * CC * 4);
  float* BUF1 = (float*)alloc((size_t)mpad * CC * 4);
  float* BUF2 = (float*)alloc((size_t)mpad * CC * 4);
  unsigned short* xb = (unsigned short*)BUF2;                 // phase A only
  unsigned short* G  = (unsigned short*)BUF2 + (size_t)mpad * CC;
  unsigned short* hb = (unsigned short*)BUF0;                 // phase C only
  float* h = BUF1;

  hipMemsetAsync(cnt_src, 0, (size_t)n * 4, stream);
  hipMemsetAsync(cnt_dst, 0, (size_t)n * 4, stream);
  hipMemsetAsync(fil,     0, (size_t)n * 4, stream);
  hipMemsetAsync(colsum,  0, CC * 4, stream);
  hipMemsetAsync(colsq,   0, CC * 4, stream);

  // graph prep
  k_count<<<(E + 255) / 256, 256, 0, stream>>>(src, dst, cnt_src, cnt_dst, E);
  k_deginv<<<(n + 255) / 256, 256, 0, stream>>>(cnt_src, dinv, n);
  k_scan<<<1, 1024, 0, stream>>>(cnt_dst, rp, n);
  k_fill<<<(E + 255) / 256, 256, 0, stream>>>(src, dst, rp, fil, colx, E);

  // converts
  int total4 = mpad * (CC / 4);
  k_conv_bf16<<<(total4 + 255) / 256, 256, 0, stream>>>(x, xb, n, total4);
  dim3 tb(32, 8);
  k_transconv<<<dim3(GNN / 32, CC / 32), tb, 0, stream>>>(W1, W1t, CC, GNN);
  k_transconv<<<dim3(NBP / 32, GNN / 32), tb, 0, stream>>>(W2, W2t, GNN, NBP);
  k_transconv<<<dim3(CC / 32, CC / 32), tb, 0, stream>>>(Wlin, Wlt, CC, CC);

  // struct encoder: G = gelu(x@W1+b1); cs = (cos,sin)(G@W2+b2)
  k_gemm<1><<<dim3(mtiles, GNN / GEMM_NT), 256, 0, stream>>>(xb, W1t, b1, (void*)G, CC, GNN);
  k_gemm<2><<<dim3(mtiles, NBP / GEMM_NT), 256, 0, stream>>>(G, W2t, b2, (void*)cs, GNN, NBP);

  // h = R x ; cur = h
  int nb = n * BB_;
  k_rotate<<<(nb + 255) / 256, 256, 0, stream>>>(x, cs, h, BUF0, nb);

  // diffusion (4 steps), ping-pong BUF0 <-> BUF2
  float* cur = BUF0;
  float* nxt = BUF2;
  for (int k = 1; k <= 4; ++k) {
    float coef = -1.0f / (float)k;   // TAU = 1
    k_diffuse<<<n, 128, 0, stream>>>(cur, nxt, h, dinv, rp, colx, coef, n);
    float* t = cur; cur = nxt; nxt = t;
  }
  // ends with cur == BUF0 -> both BUF0/BUF2 free now

  // h2 = h @ Wlin + blin
  k_conv_bf16<<<(total4 + 255) / 256, 256, 0, stream>>>(h, hb, n, total4);
  k_gemm<0><<<dim3(mtiles, CC / GEMM_NT), 256, 0, stream>>>(hb, Wlt, blin, (void*)BUF2, CC, CC);

  // out = x + R^T h2 ; then batchnorm in place
  k_rotback<<<(nb + 255) / 256, 256, 0, stream>>>(x, cs, BUF2, (float*)d_out, nb);
  k_stats<<<128, 512, 0, stream>>>((const float*)d_out, colsum, colsq, n);
  k_bnfinal<<<1, 512, 0, stream>>>(colsum, colsq, gamma, beta, scale, shift, n);
  k_norm<<<(nb + 255) / 256, 256, 0, stream>>>((float*)d_out, scale, shift, nb);
}

// Round 2
// 397.144 us; speedup vs baseline: 1.3463x; 1.3463x over previous
//
#include <hip/hip_runtime.h>

// Problem constants (BuNN layer)
#define CC   512      // channels
#define BB_  128      // bundles (4 channels each: [i=2][t=2])
#define GEMM_MT 64
#define GEMM_NT 64
#define GEMM_KT 32

typedef __attribute__((ext_vector_type(8))) short short8;
typedef __attribute__((ext_vector_type(8))) unsigned short u16x8;
typedef __attribute__((ext_vector_type(4))) float f32x4;
typedef __attribute__((ext_vector_type(2))) float f32x2;
typedef __attribute__((ext_vector_type(4))) unsigned short u16x4;

__device__ __forceinline__ unsigned short f2bf(float f) {
  union { float f; unsigned u; } v; v.f = f;
  return (unsigned short)((v.u + 0x7FFFu + ((v.u >> 16) & 1u)) >> 16);
}
__device__ __forceinline__ float bf2f(unsigned short b) {
  union { unsigned u; float f; } v; v.u = ((unsigned)b) << 16;
  return v.f;
}

// ---------------- graph prep ----------------
__global__ void k_count(const int* __restrict__ src, const int* __restrict__ dst,
                        int* __restrict__ cnt_src, int* __restrict__ cnt_dst, int E) {
  int e = blockIdx.x * blockDim.x + threadIdx.x;
  if (e < E) {
    atomicAdd(&cnt_src[src[e]], 1);
    atomicAdd(&cnt_dst[dst[e]], 1);
  }
}

__global__ void k_deginv(const int* __restrict__ cnt, float* __restrict__ dinv, int n) {
  int i = blockIdx.x * blockDim.x + threadIdx.x;
  if (i < n) dinv[i] = 1.0f / (float)cnt[i];
}

__global__ __launch_bounds__(1024) void k_scan(const int* __restrict__ cnt,
                                               int* __restrict__ rp, int n) {
  __shared__ int sm[1024];
  int tid = threadIdx.x;
  int chunk = (n + 1023) >> 10;
  int beg = tid * chunk;
  int end = beg + chunk; if (end > n) end = n;
  int s = 0;
  for (int i = beg; i < end && i < n; ++i) s += cnt[i];
  sm[tid] = s;
  __syncthreads();
  for (int off = 1; off < 1024; off <<= 1) {
    int v = (tid >= off) ? sm[tid - off] : 0;
    __syncthreads();
    sm[tid] += v;
    __syncthreads();
  }
  int run = (tid == 0) ? 0 : sm[tid - 1];
  for (int i = beg; i < end && i < n; ++i) { rp[i] = run; run += cnt[i]; }
  if (tid == 0) rp[n] = sm[1023];
}

__global__ void k_fill(const int* __restrict__ src, const int* __restrict__ dst,
                       const int* __restrict__ rp, int* __restrict__ fil,
                       int* __restrict__ col, int E) {
  int e = blockIdx.x * blockDim.x + threadIdx.x;
  if (e < E) {
    int d = dst[e];
    int p = atomicAdd(&fil[d], 1);
    col[rp[d] + p] = src[e];
  }
}

// ---------------- converts ----------------
// f32 [validRows][CC] -> bf16 [mpad][CC], zero padding rows
__global__ void k_conv_bf16(const float* __restrict__ in, unsigned short* __restrict__ out,
                            int validRows, int total4) {
  int i4 = blockIdx.x * blockDim.x + threadIdx.x;
  if (i4 >= total4) return;
  int row = i4 / (CC / 4);
  u16x4 o;
  if (row < validRows) {
    f32x4 v = ((const f32x4*)in)[i4];
    o[0] = f2bf(v[0]); o[1] = f2bf(v[1]); o[2] = f2bf(v[2]); o[3] = f2bf(v[3]);
  } else {
    o[0] = 0; o[1] = 0; o[2] = 0; o[3] = 0;
  }
  ((u16x4*)out)[i4] = o;
}

// W [K][Nw] f32  ->  Wt [Nw][K] bf16   (tiled transpose)
__global__ void k_transconv(const float* __restrict__ W, unsigned short* __restrict__ Wt,
                            int K, int Nw) {
  __shared__ float tile[32][33];
  int n0 = blockIdx.x * 32, k0 = blockIdx.y * 32;
  int tx = threadIdx.x, ty = threadIdx.y;          // 32 x 8
  for (int j = 0; j < 4; ++j)
    tile[ty + j * 8][tx] = W[(k0 + ty + j * 8) * Nw + n0 + tx];
  __syncthreads();
  for (int j = 0; j < 4; ++j)
    Wt[(n0 + ty + j * 8) * K + k0 + tx] = f2bf(tile[tx][ty + j * 8]);
}

// ---------------- GEMM: out = A[M][K](bf16) x Bt[Nw][K]^T(bf16) + bias ----------------
// EPI 0: f32 store; EPI 1: GELU(exact)->bf16 store; EPI 2: theta -> (cos,sin) float2 store
template <int EPI>
__global__ __launch_bounds__(256) void k_gemm(const unsigned short* __restrict__ A,
                                              const unsigned short* __restrict__ Bt,
                                              const float* __restrict__ bias,
                                              void* __restrict__ outp,
                                              int K, int Nw) {
  __shared__ unsigned short As[GEMM_MT][GEMM_KT + 8];
  __shared__ unsigned short Bs[GEMM_NT][GEMM_KT + 8];
  int m0 = blockIdx.x * GEMM_MT;
  int n0 = blockIdx.y * GEMM_NT;
  int tid = threadIdx.x;
  int wid = tid >> 6, lane = tid & 63;
  int wr = wid >> 1, wc = wid & 1;
  int l15 = lane & 15, kg = lane >> 4;
  int srow = tid >> 2, sseg = tid & 3;
  f32x4 acc[2][2] = {};

  for (int kt = 0; kt < K; kt += GEMM_KT) {
    *(short8*)&As[srow][sseg * 8] = *(const short8*)&A[(size_t)(m0 + srow) * K + kt + sseg * 8];
    *(short8*)&Bs[srow][sseg * 8] = *(const short8*)&Bt[(size_t)(n0 + srow) * K + kt + sseg * 8];
    __syncthreads();
    short8 af0 = *(const short8*)&As[wr * 32 + l15][kg * 8];
    short8 af1 = *(const short8*)&As[wr * 32 + 16 + l15][kg * 8];
    short8 bf0 = *(const short8*)&Bs[wc * 32 + l15][kg * 8];
    short8 bf1 = *(const short8*)&Bs[wc * 32 + 16 + l15][kg * 8];
    acc[0][0] = __builtin_amdgcn_mfma_f32_16x16x32_bf16(af0, bf0, acc[0][0], 0, 0, 0);
    acc[0][1] = __builtin_amdgcn_mfma_f32_16x16x32_bf16(af0, bf1, acc[0][1], 0, 0, 0);
    acc[1][0] = __builtin_amdgcn_mfma_f32_16x16x32_bf16(af1, bf0, acc[1][0], 0, 0, 0);
    acc[1][1] = __builtin_amdgcn_mfma_f32_16x16x32_bf16(af1, bf1, acc[1][1], 0, 0, 0);
    __syncthreads();
  }

  for (int mi = 0; mi < 2; ++mi)
    for (int ni = 0; ni < 2; ++ni)
      for (int r = 0; r < 4; ++r) {
        int row = m0 + wr * 32 + mi * 16 + kg * 4 + r;
        int colL = n0 + wc * 32 + ni * 16 + l15;
        float v = acc[mi][ni][r] + bias[colL];
        if (EPI == 0) {
          ((float*)outp)[(size_t)row * Nw + colL] = v;
        } else if (EPI == 1) {
          float g = 0.5f * v * (1.0f + erff(v * 0.70710678118654752f));
          ((unsigned short*)outp)[(size_t)row * Nw + colL] = f2bf(g);
        } else {
          float sv, cv;
          sincosf(v, &sv, &cv);
          f32x2 o; o[0] = cv; o[1] = sv;
          ((f32x2*)outp)[(size_t)row * Nw + colL] = o;
        }
      }
}

// ---------------- bundle rotation ----------------
// c0 = R x (bf16)
__global__ void k_rotate(const float* __restrict__ x, const f32x2* __restrict__ cs,
                         unsigned short* __restrict__ c0, int nb) {
  int idx = blockIdx.x * blockDim.x + threadIdx.x;
  if (idx >= nb) return;
  f32x2 a = cs[idx];
  float c = a[0], s = a[1];
  f32x4 v = ((const f32x4*)x)[idx];
  u16x4 o;
  o[0] = f2bf(c * v[0] - s * v[2]);
  o[1] = f2bf(c * v[1] - s * v[3]);
  o[2] = f2bf(s * v[0] + c * v[2]);
  o[3] = f2bf(s * v[1] + c * v[3]);
  ((u16x4*)c0)[idx] = o;
}

// out = x + R^T h2
__global__ void k_rotback(const float* __restrict__ x, const f32x2* __restrict__ cs,
                          const float* __restrict__ h2, float* __restrict__ out, int nb) {
  int idx = blockIdx.x * blockDim.x + threadIdx.x;
  if (idx >= nb) return;
  f32x2 a = cs[idx];
  float c = a[0], s = a[1];
  f32x4 v = ((const f32x4*)h2)[idx];
  f32x4 xx = ((const f32x4*)x)[idx];
  f32x4 o;
  o[0] = xx[0] + c * v[0] + s * v[2];
  o[1] = xx[1] + c * v[1] + s * v[3];
  o[2] = xx[2] - s * v[0] + c * v[2];
  o[3] = xx[3] - s * v[1] + c * v[3];
  ((f32x4*)out)[idx] = o;
}

// ---------------- diffusion (bf16): nxt = coef*(cur - dinv[v]*sum_in(cur)) ----------------
// one wave per node; lane covers 8 channels (16B loads)
__global__ __launch_bounds__(256) void k_diffuse(const unsigned short* __restrict__ cur,
                                                 unsigned short* __restrict__ nxt,
                                                 const float* __restrict__ dinv,
                                                 const int* __restrict__ rp,
                                                 const int* __restrict__ col,
                                                 float coef, int n) {
  int w = threadIdx.x >> 6, lane = threadIdx.x & 63;
  int v = blockIdx.x * 4 + w;
  if (v >= n) return;
  int beg = rp[v], end = rp[v + 1];
  const u16x8* curv = (const u16x8*)cur;
  float s[8] = {0.f,0.f,0.f,0.f,0.f,0.f,0.f,0.f};
  for (int e = beg; e < end; ++e) {
    int u = col[e];
    u16x8 r = curv[(size_t)u * 64 + lane];
    #pragma unroll
    for (int j = 0; j < 8; ++j) s[j] += bf2f(r[j]);
  }
  float di = dinv[v];
  u16x8 cv = curv[(size_t)v * 64 + lane];
  u16x8 o;
  #pragma unroll
  for (int j = 0; j < 8; ++j) o[j] = f2bf((bf2f(cv[j]) - s[j] * di) * coef);
  ((u16x8*)nxt)[(size_t)v * 64 + lane] = o;
}

// ---------------- deferred h-sum: hb = bf16(sum_{k=0..4} c_k), pad rows = 0 ----------------
__global__ void k_hsum(const unsigned short* __restrict__ c0, const unsigned short* __restrict__ c1,
                       const unsigned short* __restrict__ c2, const unsigned short* __restrict__ c3,
                       const unsigned short* __restrict__ c4, unsigned short* __restrict__ hb,
                       int n, int total8) {
  int i = blockIdx.x * blockDim.x + threadIdx.x;
  if (i >= total8) return;
  int row = i >> 6;
  u16x8 o;
  if (row < n) {
    u16x8 a0 = ((const u16x8*)c0)[i];
    u16x8 a1 = ((const u16x8*)c1)[i];
    u16x8 a2 = ((const u16x8*)c2)[i];
    u16x8 a3 = ((const u16x8*)c3)[i];
    u16x8 a4 = ((const u16x8*)c4)[i];
    #pragma unroll
    for (int j = 0; j < 8; ++j)
      o[j] = f2bf(bf2f(a0[j]) + bf2f(a1[j]) + bf2f(a2[j]) + bf2f(a3[j]) + bf2f(a4[j]));
  } else {
    #pragma unroll
    for (int j = 0; j < 8; ++j) o[j] = 0;
  }
  ((u16x8*)hb)[i] = o;
}

// ---------------- batch norm ----------------
__global__ __launch_bounds__(512) void k_stats(const float* __restrict__ out,
                                               float* __restrict__ sum, float* __restrict__ sumsq,
                                               int n) {
  int c = threadIdx.x;
  float s = 0.f, s2 = 0.f;
  for (int r = blockIdx.x; r < n; r += gridDim.x) {
    float v = out[(size_t)r * CC + c];
    s += v; s2 += v * v;
  }
  atomicAdd(&sum[c], s);
  atomicAdd(&sumsq[c], s2);
}

__global__ void k_bnfinal(const float* __restrict__ sum, const float* __restrict__ sumsq,
                          const float* __restrict__ gamma, const float* __restrict__ beta,
                          float* __restrict__ scale, float* __restrict__ shift, int n) {
  int c = threadIdx.x;
  float inv = 1.0f / (float)n;
  float mean = sum[c] * inv;
  float var = sumsq[c] * inv - mean * mean;
  float sc = gamma[c] * rsqrtf(var + 1e-5f);
  scale[c] = sc;
  shift[c] = beta[c] - mean * sc;
}

__global__ void k_norm(float* __restrict__ out, const float* __restrict__ scale,
                       const float* __restrict__ shift, int n4) {
  int i = blockIdx.x * blockDim.x + threadIdx.x;
  if (i >= n4) return;
  int c4 = i & (CC / 4 - 1);
  f32x4 v = ((f32x4*)out)[i];
  f32x4 sc = ((const f32x4*)scale)[c4];
  f32x4 sh = ((const f32x4*)shift)[c4];
  ((f32x4*)out)[i] = v * sc + sh;
}

// ---------------- orchestration ----------------
extern "C" void kernel_launch(void* const* d_in, const int* in_sizes, int n_in,
                              void* d_out, int out_size, void* d_ws, size_t ws_size,
                              hipStream_t stream) {
  (void)n_in; (void)out_size; (void)ws_size;
  const float* x    = (const float*)d_in[0];
  const float* W1   = (const float*)d_in[1];
  const float* b1   = (const float*)d_in[2];
  const float* W2   = (const float*)d_in[3];
  const float* b2   = (const float*)d_in[4];
  const float* Wlin = (const float*)d_in[5];
  const float* blin = (const float*)d_in[6];
  const float* gamma = (const float*)d_in[7];
  const float* beta  = (const float*)d_in[8];
  const int*   ei    = (const int*)d_in[9];

  const int n   = in_sizes[0] / CC;          // 20000
  const int E   = in_sizes[9] / 2;           // 160000
  const int GNN = in_sizes[2];               // 512
  const int NBP = in_sizes[4];               // 128
  const int* src = ei;
  const int* dst = ei + E;
  const int mtiles = (n + GEMM_MT - 1) / GEMM_MT;
  const int mpad = mtiles * GEMM_MT;         // 20032
  const size_t SB = (size_t)mpad * CC;       // elements per bf16 buffer

  char* ws = (char*)d_ws;
  size_t off = 0;
  auto alloc = [&](size_t bytes) -> void* {
    void* p = ws + off;
    off = (off + bytes + 255) & ~(size_t)255;
    return p;
  };
  int*   cnt_src = (int*)alloc((size_t)n * 4);
  int*   cnt_dst = (int*)alloc((size_t)n * 4);
  int*   fil     = (int*)alloc((size_t)n * 4);
  int*   rp      = (int*)alloc((size_t)(n + 1) * 4);
  int*   colx    = (int*)alloc((size_t)E * 4);
  float* dinv    = (float*)alloc((size_t)n * 4);
  float* colsum  = (float*)alloc(CC * 4);
  float* colsq   = (float*)alloc(CC * 4);
  float* scale   = (float*)alloc(CC * 4);
  float* shift   = (float*)alloc(CC * 4);
  unsigned short* W1t = (unsigned short*)alloc((size_t)GNN * CC * 2);
  unsigned short* W2t = (unsigned short*)alloc((size_t)NBP * GNN * 2);
  unsigned short* Wlt = (unsigned short*)alloc((size_t)CC * CC * 2);
  f32x2* cs = (f32x2*)alloc((size_t)mpad * BB_ * 8);
  unsigned short* c0   = (unsigned short*)alloc(SB * 2);   // phase A: xb
  unsigned short* c1   = (unsigned short*)alloc(SB * 2);   // phase A: G
  unsigned short* slab = (unsigned short*)alloc(SB * 2 * 3); // c2,c3,c4; later OUT3 f32
  unsigned short* c2 = slab;
  unsigned short* c3 = slab + SB;
  unsigned short* c4 = slab + 2 * SB;
  unsigned short* xb = c0;
  unsigned short* G  = c1;
  unsigned short* hb = c4;                   // hsum writes element-wise over c4 (safe)
  float* OUT3 = (float*)slab;                // 41MB over c2+c3 (dead after hsum)

  hipMemsetAsync(cnt_src, 0, (size_t)n * 4, stream);
  hipMemsetAsync(cnt_dst, 0, (size_t)n * 4, stream);
  hipMemsetAsync(fil,     0, (size_t)n * 4, stream);
  hipMemsetAsync(colsum,  0, CC * 4, stream);
  hipMemsetAsync(colsq,   0, CC * 4, stream);

  // graph prep
  k_count<<<(E + 255) / 256, 256, 0, stream>>>(src, dst, cnt_src, cnt_dst, E);
  k_deginv<<<(n + 255) / 256, 256, 0, stream>>>(cnt_src, dinv, n);
  k_scan<<<1, 1024, 0, stream>>>(cnt_dst, rp, n);
  k_fill<<<(E + 255) / 256, 256, 0, stream>>>(src, dst, rp, fil, colx, E);

  // converts
  int total4 = mpad * (CC / 4);
  k_conv_bf16<<<(total4 + 255) / 256, 256, 0, stream>>>(x, xb, n, total4);
  dim3 tb(32, 8);
  k_transconv<<<dim3(GNN / 32, CC / 32), tb, 0, stream>>>(W1, W1t, CC, GNN);
  k_transconv<<<dim3(NBP / 32, GNN / 32), tb, 0, stream>>>(W2, W2t, GNN, NBP);
  k_transconv<<<dim3(CC / 32, CC / 32), tb, 0, stream>>>(Wlin, Wlt, CC, CC);

  // struct encoder: G = gelu(x@W1+b1); cs = (cos,sin)(G@W2+b2)
  k_gemm<1><<<dim3(mtiles, GNN / GEMM_NT), 256, 0, stream>>>(xb, W1t, b1, (void*)G, CC, GNN);
  k_gemm<2><<<dim3(mtiles, NBP / GEMM_NT), 256, 0, stream>>>(G, W2t, b2, (void*)cs, GNN, NBP);

  // c0 = R x (bf16)   [overwrites xb region — GEMM1 already done]
  int nb = n * BB_;
  k_rotate<<<(nb + 255) / 256, 256, 0, stream>>>(x, cs, c0, nb);

  // diffusion: c0 -> c1 -> c2 -> c3 -> c4  (c1 overwrites G — GEMM2 done)
  unsigned short* chain[5] = {c0, c1, c2, c3, c4};
  for (int k = 1; k <= 4; ++k) {
    float coef = -1.0f / (float)k;   // TAU = 1
    k_diffuse<<<(n + 3) / 4, 256, 0, stream>>>(chain[k - 1], chain[k], dinv, rp, colx, coef, n);
  }

  // hb = bf16(c0+c1+c2+c3+c4)  (element-wise; hb aliases c4)
  int total8 = mpad * (CC / 8);
  k_hsum<<<(total8 + 255) / 256, 256, 0, stream>>>(c0, c1, c2, c3, c4, hb, n, total8);

  // h2 = hb @ Wlin + blin  -> OUT3 (f32, overlays c2/c3)
  k_gemm<0><<<dim3(mtiles, CC / GEMM_NT), 256, 0, stream>>>(hb, Wlt, blin, (void*)OUT3, CC, CC);

  // out = x + R^T h2 ; then batchnorm in place
  k_rotback<<<(nb + 255) / 256, 256, 0, stream>>>(x, cs, OUT3, (float*)d_out, nb);
  k_stats<<<128, 512, 0, stream>>>((const float*)d_out, colsum, colsq, n);
  k_bnfinal<<<1, 512, 0, stream>>>(colsum, colsq, gamma, beta, scale, shift, n);
  k_norm<<<(nb + 255) / 256, 256, 0, stream>>>((float*)d_out, scale, shift, nb);
}